// Round 2
// baseline (906.055 us; speedup 1.0000x reference)
//
#include <hip/hip_runtime.h>

#define SCAN_CHUNK 1024
#define BSHIFT 6
#define BSIZE 64          // nodes per bucket
#define MAXNB 1600        // max buckets (n<=102400)

// ---------------- bucket histogram (LDS-aggregated) ----------------

__global__ __launch_bounds__(256) void bucket_hist_kernel(const int* __restrict__ dst,
                                                          int* __restrict__ bcnt, int E, int nb) {
    __shared__ int lh[MAXNB];
    for (int i = threadIdx.x; i < nb; i += 256) lh[i] = 0;
    __syncthreads();
    int e = blockIdx.x * blockDim.x + threadIdx.x;
    int stride = gridDim.x * blockDim.x;
    for (; e < E; e += stride) atomicAdd(&lh[dst[e] >> BSHIFT], 1);
    __syncthreads();
    for (int i = threadIdx.x; i < nb; i += 256) {
        int v = lh[i];
        if (v) atomicAdd(&bcnt[i], v);
    }
}

// single-block exclusive scan of bucket counts -> bucket_ptr
__global__ __launch_bounds__(256) void bucket_scan_kernel(const int* __restrict__ bcnt,
                                                          int* __restrict__ bptr, int nb) {
    __shared__ int sdata[256];
    int per = (nb + 255) / 256;
    int base = threadIdx.x * per;
    int tsum = 0;
    for (int j = 0; j < per; j++) { int i = base + j; tsum += (i < nb) ? bcnt[i] : 0; }
    sdata[threadIdx.x] = tsum;
    __syncthreads();
    for (int s = 1; s < 256; s <<= 1) {
        int v = (threadIdx.x >= s) ? sdata[threadIdx.x - s] : 0;
        __syncthreads();
        sdata[threadIdx.x] += v;
        __syncthreads();
    }
    int off = (threadIdx.x == 0) ? 0 : sdata[threadIdx.x - 1];
    for (int j = 0; j < per; j++) {
        int i = base + j;
        if (i < nb) { bptr[i] = off; off += bcnt[i]; }
    }
    if (threadIdx.x == 255) bptr[nb] = sdata[255];
}

// bin edges into bucket regions: writes fill whole cache lines per bucket
__global__ __launch_bounds__(256) void bin_kernel(const int* __restrict__ src,
                                                  const int* __restrict__ dst,
                                                  const int* __restrict__ bptr,
                                                  int* __restrict__ bfill,
                                                  int2* __restrict__ binned, int E) {
    int e = blockIdx.x * blockDim.x + threadIdx.x;
    int stride = gridDim.x * blockDim.x;
    for (; e < E; e += stride) {
        int s = src[e], d = dst[e];
        int b = d >> BSHIFT;
        int pos = atomicAdd(&bfill[b], 1);
        binned[bptr[b] + pos] = make_int2(s, d);
    }
}

// per-bucket node histogram from binned edges (LDS counters, no global atomics)
__global__ __launch_bounds__(256) void bucket_node_hist_kernel(const int2* __restrict__ binned,
                                                               const int* __restrict__ bptr,
                                                               int* __restrict__ cnt, int n) {
    __shared__ int c[BSIZE];
    int b = blockIdx.x;
    if (threadIdx.x < BSIZE) c[threadIdx.x] = 0;
    __syncthreads();
    int beg = bptr[b], end = bptr[b + 1];
    for (int e = beg + threadIdx.x; e < end; e += 256)
        atomicAdd(&c[binned[e].y & (BSIZE - 1)], 1);
    __syncthreads();
    int node = (b << BSHIFT) + threadIdx.x;
    if (threadIdx.x < BSIZE && node < n) cnt[node] = c[threadIdx.x];
}

// ---------------- global scan over node counts (unchanged) ----------------

__global__ void block_sum_kernel(const int* __restrict__ cnt, int* __restrict__ partials, int n) {
    __shared__ int sdata[256];
    int base = blockIdx.x * SCAN_CHUNK;
    int sum = 0;
    for (int i = threadIdx.x; i < SCAN_CHUNK; i += 256) {
        int idx = base + i;
        sum += (idx < n) ? cnt[idx] : 0;
    }
    sdata[threadIdx.x] = sum;
    __syncthreads();
    for (int s = 128; s > 0; s >>= 1) {
        if (threadIdx.x < s) sdata[threadIdx.x] += sdata[threadIdx.x + s];
        __syncthreads();
    }
    if (threadIdx.x == 0) partials[blockIdx.x] = sdata[0];
}

__global__ void scan_partials_kernel(int* __restrict__ partials, int nb,
                                     int* __restrict__ row_ptr, int n) {
    if (threadIdx.x == 0 && blockIdx.x == 0) {
        int acc = 0;
        for (int i = 0; i < nb; i++) { int v = partials[i]; partials[i] = acc; acc += v; }
        row_ptr[n] = acc;
    }
}

__global__ void scan_write_kernel(const int* __restrict__ cnt, const int* __restrict__ partials,
                                  int* __restrict__ row_ptr, int n) {
    __shared__ int sdata[256];
    int base = blockIdx.x * SCAN_CHUNK;
    int tbase = base + threadIdx.x * 4;
    int vals[4];
    int tsum = 0;
    #pragma unroll
    for (int j = 0; j < 4; j++) {
        int idx = tbase + j;
        vals[j] = (idx < n) ? cnt[idx] : 0;
        tsum += vals[j];
    }
    sdata[threadIdx.x] = tsum;
    __syncthreads();
    for (int s = 1; s < 256; s <<= 1) {
        int v = (threadIdx.x >= s) ? sdata[threadIdx.x - s] : 0;
        __syncthreads();
        sdata[threadIdx.x] += v;
        __syncthreads();
    }
    int excl = (threadIdx.x == 0) ? 0 : sdata[threadIdx.x - 1];
    int offset = partials[blockIdx.x] + excl;
    #pragma unroll
    for (int j = 0; j < 4; j++) {
        int idx = tbase + j;
        if (idx < n) row_ptr[idx] = offset;
        offset += vals[j];
    }
}

// per-bucket final scatter: writes land in a contiguous ~8-16KB window
__global__ __launch_bounds__(256) void bucket_scatter_kernel(const int2* __restrict__ binned,
                                                             const int* __restrict__ bptr,
                                                             const int* __restrict__ row_ptr,
                                                             int* __restrict__ srcidx, int n) {
    __shared__ int rp[BSIZE];
    __shared__ int fill[BSIZE];
    int b = blockIdx.x;
    int base = b << BSHIFT;
    if (threadIdx.x < BSIZE) {
        int node = base + threadIdx.x;
        rp[threadIdx.x] = (node < n) ? row_ptr[node] : 0;
        fill[threadIdx.x] = 0;
    }
    __syncthreads();
    int beg = bptr[b], end = bptr[b + 1];
    for (int e = beg + threadIdx.x; e < end; e += 256) {
        int2 p = binned[e];
        int l = p.y & (BSIZE - 1);
        int pos = atomicAdd(&fill[l], 1);
        srcidx[rp[l] + pos] = p.x;
    }
}

__global__ void dinv_kernel(const int* __restrict__ row_ptr, float* __restrict__ dinv, int n) {
    int i = blockIdx.x * blockDim.x + threadIdx.x;
    if (i < n) {
        int deg = row_ptr[i + 1] - row_ptr[i] + 1;  // +1 self-loop
        dinv[i] = rsqrtf((float)deg);
    }
}

// ---------------- dense transform: g[r][c] = dinv[r] * sum_k in[r][k]*W[k][c] ----------------

__global__ __launch_bounds__(256) void transform_kernel(const float* __restrict__ in,
                                                        const float* __restrict__ W,
                                                        const float* __restrict__ dinv,
                                                        float* __restrict__ g, int n) {
    __shared__ float Ws[64 * 64];
    for (int i = threadIdx.x; i < 64 * 64; i += 256) Ws[i] = W[i];
    __syncthreads();
    int lane = threadIdx.x & 63;
    int wave = (blockIdx.x * 256 + threadIdx.x) >> 6;
    int nwaves = gridDim.x * 4;
    for (int r = wave; r < n; r += nwaves) {
        float xv = in[r * 64 + lane];
        float acc = 0.f;
        #pragma unroll
        for (int k = 0; k < 64; k++) {
            float xk = __shfl(xv, k, 64);
            acc = fmaf(xk, Ws[k * 64 + lane], acc);
        }
        g[r * 64 + lane] = acc * dinv[r];
    }
}

// ---------------- aggregate: out[i] = dinv[i]*(g[i] + sum_{j in N(i)} g[j]) + b ----------------

__global__ __launch_bounds__(256) void aggregate_kernel(const float* __restrict__ g,
                                                        const int* __restrict__ row_ptr,
                                                        const int* __restrict__ srcidx,
                                                        const float* __restrict__ dinv,
                                                        const float* __restrict__ b,
                                                        float* __restrict__ out, int n, int relu) {
    int lane = threadIdx.x & 63;
    int node = (blockIdx.x * 256 + threadIdx.x) >> 6;
    if (node >= n) return;
    node = __builtin_amdgcn_readfirstlane(node);
    int beg = row_ptr[node];
    int end = row_ptr[node + 1];
    float acc = g[node * 64 + lane];  // self-loop (g already has dinv factor)
    int e = beg;
    for (; e + 4 <= end; e += 4) {
        int s0 = srcidx[e + 0], s1 = srcidx[e + 1], s2 = srcidx[e + 2], s3 = srcidx[e + 3];
        float v0 = g[s0 * 64 + lane];
        float v1 = g[s1 * 64 + lane];
        float v2 = g[s2 * 64 + lane];
        float v3 = g[s3 * 64 + lane];
        acc += (v0 + v1) + (v2 + v3);
    }
    for (; e < end; ++e) acc += g[srcidx[e] * 64 + lane];
    float o = fmaf(dinv[node], acc, b[lane]);
    out[node * 64 + lane] = relu ? fmaxf(o, 0.f) : o;
}

extern "C" void kernel_launch(void* const* d_in, const int* in_sizes, int n_in,
                              void* d_out, int out_size, void* d_ws, size_t ws_size,
                              hipStream_t stream) {
    const float* x  = (const float*)d_in[0];
    const int*   ei = (const int*)d_in[1];
    const float* W1 = (const float*)d_in[2];
    const float* b1 = (const float*)d_in[3];
    const float* W2 = (const float*)d_in[4];
    const float* b2 = (const float*)d_in[5];
    float* out = (float*)d_out;

    const int n = in_sizes[0] / 64;      // 100000
    const int E = in_sizes[1] / 2;       // 3200000
    const int* src = ei;
    const int* dst = ei + E;
    const int NB = (n + BSIZE - 1) >> BSHIFT;   // 1563 buckets

    // workspace carve-up (256B aligned)
    char* ws = (char*)d_ws;
    size_t off = 0;
    auto carve = [&](size_t bytes) { char* p = ws + off; off = (off + bytes + 255) & ~(size_t)255; return p; };
    int*   cnt      = (int*)  carve((size_t)n * 4);
    int*   row_ptr  = (int*)  carve((size_t)(n + 1) * 4);
    int*   partials = (int*)  carve(4096);
    float* dinv     = (float*)carve((size_t)n * 4);
    int*   bcnt     = (int*)  carve((size_t)NB * 4);      // bcnt+bfill contiguous: one memset
    int*   bfill    = (int*)  carve((size_t)NB * 4);
    int*   bptr     = (int*)  carve((size_t)(NB + 1) * 4);
    int*   srcidx   = (int*)  carve((size_t)E * 4);
    int2*  binned   = (int2*) carve((size_t)E * 8);
    float* g        = (float*)binned;    // alias: binned dead before transforms run

    const int nb_scan = (n + SCAN_CHUNK - 1) / SCAN_CHUNK;

    // ---- CSR build via bucket partition (shared by both layers) ----
    hipMemsetAsync(bcnt, 0, (size_t)(bptr - bcnt) * 4 + 0, stream);  // zero bcnt+bfill (+pad)
    bucket_hist_kernel<<<512, 256, 0, stream>>>(dst, bcnt, E, NB);
    bucket_scan_kernel<<<1, 256, 0, stream>>>(bcnt, bptr, NB);
    bin_kernel<<<4096, 256, 0, stream>>>(src, dst, bptr, bfill, binned, E);
    bucket_node_hist_kernel<<<NB, 256, 0, stream>>>(binned, bptr, cnt, n);
    block_sum_kernel<<<nb_scan, 256, 0, stream>>>(cnt, partials, n);
    scan_partials_kernel<<<1, 64, 0, stream>>>(partials, nb_scan, row_ptr, n);
    scan_write_kernel<<<nb_scan, 256, 0, stream>>>(cnt, partials, row_ptr, n);
    bucket_scatter_kernel<<<NB, 256, 0, stream>>>(binned, bptr, row_ptr, srcidx, n);
    dinv_kernel<<<(n + 255) / 256, 256, 0, stream>>>(row_ptr, dinv, n);

    const int agg_grid = (n * 64 + 255) / 256;   // one wave per node

    // ---- layer 1: g = (x@W1)*dinv ; h1 = relu(dinv*(agg(g)+g)+b1) -> d_out ----
    transform_kernel<<<1024, 256, 0, stream>>>(x, W1, dinv, g, n);
    aggregate_kernel<<<agg_grid, 256, 0, stream>>>(g, row_ptr, srcidx, dinv, b1, out, n, 1);

    // ---- layer 2: g = (h1@W2)*dinv ; out = dinv*(agg(g)+g)+b2 ----
    transform_kernel<<<1024, 256, 0, stream>>>(out, W2, dinv, g, n);
    aggregate_kernel<<<agg_grid, 256, 0, stream>>>(g, row_ptr, srcidx, dinv, b2, out, n, 0);
}

// Round 3
// 472.979 us; speedup vs baseline: 1.9156x; 1.9156x over previous
//
#include <hip/hip_runtime.h>

#define SCAN_CHUNK 1024
#define NCH 256          // edge chunks (= pass-A/B grid)
#define BSHIFT 8
#define BNODES 256       // nodes per bucket
#define MAXNB 512        // max buckets (n <= 131072)

// ---------------- pass A: per-chunk bucket histogram ----------------

__global__ __launch_bounds__(256) void chunk_hist_kernel(const int* __restrict__ dst,
                                                         int* __restrict__ histG,
                                                         int E, int NB, int chunk) {
    __shared__ int lh[MAXNB];
    int c = blockIdx.x;
    for (int i = threadIdx.x; i < NB; i += 256) lh[i] = 0;
    __syncthreads();
    int beg = c * chunk, end = min(beg + chunk, E);
    for (int e = beg + threadIdx.x; e < end; e += 256) atomicAdd(&lh[dst[e] >> BSHIFT], 1);
    __syncthreads();
    for (int i = threadIdx.x; i < NB; i += 256) histG[i * NCH + c] = lh[i];  // bucket-major
}

// ---------------- generic 3-kernel exclusive scan (in -> out, out[L]=total) ----------------

__global__ void block_sum_kernel(const int* __restrict__ in, int* __restrict__ partials, int L) {
    __shared__ int sdata[256];
    int base = blockIdx.x * SCAN_CHUNK;
    int sum = 0;
    for (int i = threadIdx.x; i < SCAN_CHUNK; i += 256) {
        int idx = base + i;
        sum += (idx < L) ? in[idx] : 0;
    }
    sdata[threadIdx.x] = sum;
    __syncthreads();
    for (int s = 128; s > 0; s >>= 1) {
        if (threadIdx.x < s) sdata[threadIdx.x] += sdata[threadIdx.x + s];
        __syncthreads();
    }
    if (threadIdx.x == 0) partials[blockIdx.x] = sdata[0];
}

__global__ void scan_partials_kernel(int* __restrict__ partials, int nb,
                                     int* __restrict__ out, int L) {
    if (threadIdx.x == 0 && blockIdx.x == 0) {
        int acc = 0;
        for (int i = 0; i < nb; i++) { int v = partials[i]; partials[i] = acc; acc += v; }
        out[L] = acc;  // total
    }
}

__global__ void scan_write_kernel(const int* __restrict__ in, const int* __restrict__ partials,
                                  int* __restrict__ out, int L) {
    __shared__ int sdata[256];
    int base = blockIdx.x * SCAN_CHUNK;
    int tbase = base + threadIdx.x * 4;
    int vals[4];
    int tsum = 0;
    #pragma unroll
    for (int j = 0; j < 4; j++) {
        int idx = tbase + j;
        vals[j] = (idx < L) ? in[idx] : 0;
        tsum += vals[j];
    }
    sdata[threadIdx.x] = tsum;
    __syncthreads();
    for (int s = 1; s < 256; s <<= 1) {
        int v = (threadIdx.x >= s) ? sdata[threadIdx.x - s] : 0;
        __syncthreads();
        sdata[threadIdx.x] += v;
        __syncthreads();
    }
    int excl = (threadIdx.x == 0) ? 0 : sdata[threadIdx.x - 1];
    int offset = partials[blockIdx.x] + excl;
    #pragma unroll
    for (int j = 0; j < 4; j++) {
        int idx = tbase + j;
        if (idx < L) out[idx] = offset;
        offset += vals[j];
    }
}

// ---------------- pass B: scatter into (bucket,chunk) windows via LDS cursors ----------------

__global__ __launch_bounds__(256) void chunk_scatter_kernel(const int* __restrict__ src,
                                                            const int* __restrict__ dst,
                                                            const int* __restrict__ histBase,
                                                            int2* __restrict__ binned,
                                                            int E, int NB, int chunk) {
    __shared__ int cur[MAXNB];
    int c = blockIdx.x;
    for (int i = threadIdx.x; i < NB; i += 256) cur[i] = histBase[i * NCH + c];
    __syncthreads();
    int beg = c * chunk, end = min(beg + chunk, E);
    for (int e = beg + threadIdx.x; e < end; e += 256) {
        int s = src[e], d = dst[e];
        int pos = atomicAdd(&cur[d >> BSHIFT], 1);
        binned[pos] = make_int2(s, d);
    }
}

// ---------------- per-bucket node histogram (LDS counters) ----------------

__global__ __launch_bounds__(256) void bucket_node_hist_kernel(const int2* __restrict__ binned,
                                                               const int* __restrict__ histBase,
                                                               int* __restrict__ cnt, int n) {
    __shared__ int c[BNODES];
    int b = blockIdx.x;
    c[threadIdx.x] = 0;
    __syncthreads();
    int beg = histBase[b * NCH], end = histBase[(b + 1) * NCH];
    for (int e = beg + threadIdx.x; e < end; e += 256)
        atomicAdd(&c[binned[e].y & (BNODES - 1)], 1);
    __syncthreads();
    int node = (b << BSHIFT) + threadIdx.x;
    if (node < n) cnt[node] = c[threadIdx.x];
}

// ---------------- per-bucket final scatter into CSR (contiguous L2-resident window) ----------------

__global__ __launch_bounds__(256) void bucket_scatter_kernel(const int2* __restrict__ binned,
                                                             const int* __restrict__ histBase,
                                                             const int* __restrict__ row_ptr,
                                                             int* __restrict__ srcidx, int n) {
    __shared__ int rp[BNODES];
    __shared__ int fill[BNODES];
    int b = blockIdx.x;
    int node = (b << BSHIFT) + threadIdx.x;
    rp[threadIdx.x] = (node < n) ? row_ptr[node] : 0;
    fill[threadIdx.x] = 0;
    __syncthreads();
    int beg = histBase[b * NCH], end = histBase[(b + 1) * NCH];
    for (int e = beg + threadIdx.x; e < end; e += 256) {
        int2 p = binned[e];
        int l = p.y & (BNODES - 1);
        int pos = atomicAdd(&fill[l], 1);
        srcidx[rp[l] + pos] = p.x;
    }
}

__global__ void dinv_kernel(const int* __restrict__ row_ptr, float* __restrict__ dinv, int n) {
    int i = blockIdx.x * blockDim.x + threadIdx.x;
    if (i < n) {
        int deg = row_ptr[i + 1] - row_ptr[i] + 1;  // +1 self-loop
        dinv[i] = rsqrtf((float)deg);
    }
}

// ---------------- dense transform: g[r][c] = dinv[r] * sum_k in[r][k]*W[k][c] ----------------

__global__ __launch_bounds__(256) void transform_kernel(const float* __restrict__ in,
                                                        const float* __restrict__ W,
                                                        const float* __restrict__ dinv,
                                                        float* __restrict__ g, int n) {
    __shared__ float Ws[64 * 64];
    for (int i = threadIdx.x; i < 64 * 64; i += 256) Ws[i] = W[i];
    __syncthreads();
    int lane = threadIdx.x & 63;
    int wave = (blockIdx.x * 256 + threadIdx.x) >> 6;
    int nwaves = gridDim.x * 4;
    for (int r = wave; r < n; r += nwaves) {
        float xv = in[r * 64 + lane];
        float acc = 0.f;
        #pragma unroll
        for (int k = 0; k < 64; k++) {
            float xk = __shfl(xv, k, 64);
            acc = fmaf(xk, Ws[k * 64 + lane], acc);
        }
        g[r * 64 + lane] = acc * dinv[r];
    }
}

// ---------------- aggregate: out[i] = dinv[i]*(g[i] + sum_{j in N(i)} g[j]) + b ----------------

__global__ __launch_bounds__(256) void aggregate_kernel(const float* __restrict__ g,
                                                        const int* __restrict__ row_ptr,
                                                        const int* __restrict__ srcidx,
                                                        const float* __restrict__ dinv,
                                                        const float* __restrict__ b,
                                                        float* __restrict__ out, int n, int relu) {
    int lane = threadIdx.x & 63;
    int node = (blockIdx.x * 256 + threadIdx.x) >> 6;
    if (node >= n) return;
    node = __builtin_amdgcn_readfirstlane(node);
    int beg = row_ptr[node];
    int end = row_ptr[node + 1];
    float acc = g[node * 64 + lane];  // self-loop (g already has dinv factor)
    int e = beg;
    for (; e + 4 <= end; e += 4) {
        int s0 = srcidx[e + 0], s1 = srcidx[e + 1], s2 = srcidx[e + 2], s3 = srcidx[e + 3];
        float v0 = g[s0 * 64 + lane];
        float v1 = g[s1 * 64 + lane];
        float v2 = g[s2 * 64 + lane];
        float v3 = g[s3 * 64 + lane];
        acc += (v0 + v1) + (v2 + v3);
    }
    for (; e < end; ++e) acc += g[srcidx[e] * 64 + lane];
    float o = fmaf(dinv[node], acc, b[lane]);
    out[node * 64 + lane] = relu ? fmaxf(o, 0.f) : o;
}

extern "C" void kernel_launch(void* const* d_in, const int* in_sizes, int n_in,
                              void* d_out, int out_size, void* d_ws, size_t ws_size,
                              hipStream_t stream) {
    const float* x  = (const float*)d_in[0];
    const int*   ei = (const int*)d_in[1];
    const float* W1 = (const float*)d_in[2];
    const float* b1 = (const float*)d_in[3];
    const float* W2 = (const float*)d_in[4];
    const float* b2 = (const float*)d_in[5];
    float* out = (float*)d_out;

    const int n = in_sizes[0] / 64;      // 100000
    const int E = in_sizes[1] / 2;       // 3200000
    const int* src = ei;
    const int* dst = ei + E;
    const int NB = (n + BNODES - 1) >> BSHIFT;         // 391 buckets
    const int chunk = (E + NCH - 1) / NCH;             // 12500 edges/chunk
    const int L = NB * NCH;                            // histogram length

    // workspace carve-up (256B aligned)
    char* ws = (char*)d_ws;
    size_t off = 0;
    auto carve = [&](size_t bytes) { char* p = ws + off; off = (off + bytes + 255) & ~(size_t)255; return p; };
    int*   cnt      = (int*)  carve((size_t)n * 4);
    int*   row_ptr  = (int*)  carve((size_t)(n + 1) * 4);
    int*   partials = (int*)  carve(4096);
    float* dinv     = (float*)carve((size_t)n * 4);
    int*   histG    = (int*)  carve((size_t)L * 4);        // per-(bucket,chunk) counts
    int*   histBase = (int*)  carve((size_t)(L + 1) * 4);  // scanned offsets
    int*   srcidx   = (int*)  carve((size_t)E * 4);
    int2*  binned   = (int2*) carve((size_t)E * 8);
    float* g        = (float*)binned;    // alias: binned dead before transforms run

    const int nbs_hist = (L + SCAN_CHUNK - 1) / SCAN_CHUNK;   // 98
    const int nbs_node = (n + SCAN_CHUNK - 1) / SCAN_CHUNK;   // 98

    // ---- CSR build via chunked two-pass radix partition (shared by both layers) ----
    chunk_hist_kernel<<<NCH, 256, 0, stream>>>(dst, histG, E, NB, chunk);
    block_sum_kernel<<<nbs_hist, 256, 0, stream>>>(histG, partials, L);
    scan_partials_kernel<<<1, 64, 0, stream>>>(partials, nbs_hist, histBase, L);
    scan_write_kernel<<<nbs_hist, 256, 0, stream>>>(histG, partials, histBase, L);
    chunk_scatter_kernel<<<NCH, 256, 0, stream>>>(src, dst, histBase, binned, E, NB, chunk);
    bucket_node_hist_kernel<<<NB, 256, 0, stream>>>(binned, histBase, cnt, n);
    block_sum_kernel<<<nbs_node, 256, 0, stream>>>(cnt, partials, n);
    scan_partials_kernel<<<1, 64, 0, stream>>>(partials, nbs_node, row_ptr, n);
    scan_write_kernel<<<nbs_node, 256, 0, stream>>>(cnt, partials, row_ptr, n);
    bucket_scatter_kernel<<<NB, 256, 0, stream>>>(binned, histBase, row_ptr, srcidx, n);
    dinv_kernel<<<(n + 255) / 256, 256, 0, stream>>>(row_ptr, dinv, n);

    const int agg_grid = (n * 64 + 255) / 256;   // one wave per node

    // ---- layer 1: g = (x@W1)*dinv ; h1 = relu(dinv*(agg(g)+g)+b1) -> d_out ----
    transform_kernel<<<1024, 256, 0, stream>>>(x, W1, dinv, g, n);
    aggregate_kernel<<<agg_grid, 256, 0, stream>>>(g, row_ptr, srcidx, dinv, b1, out, n, 1);

    // ---- layer 2: g = (h1@W2)*dinv ; out = dinv*(agg(g)+g)+b2 ----
    transform_kernel<<<1024, 256, 0, stream>>>(out, W2, dinv, g, n);
    aggregate_kernel<<<agg_grid, 256, 0, stream>>>(g, row_ptr, srcidx, dinv, b2, out, n, 0);
}

// Round 4
// 366.103 us; speedup vs baseline: 2.4749x; 1.2919x over previous
//
#include <hip/hip_runtime.h>

typedef unsigned short ushort_t;
typedef unsigned int uint_t;

#define SCAN_CHUNK 1024
#define NCH 256          // edge chunks (= pass-A/B grid)
#define BSHIFT 8
#define BNODES 256       // nodes per bucket
#define MAXNB 512        // max buckets (n <= 131072)

__device__ __forceinline__ ushort_t f32_to_bf16(float f) {
    uint_t u = __float_as_uint(f);
    return (ushort_t)((u + 0x7FFF + ((u >> 16) & 1)) >> 16);  // RNE
}
__device__ __forceinline__ float bf16_to_f32(ushort_t h) {
    return __uint_as_float((uint_t)h << 16);
}

// ---------------- pass A: per-chunk bucket histogram ----------------

__global__ __launch_bounds__(256) void chunk_hist_kernel(const int* __restrict__ dst,
                                                         int* __restrict__ histG,
                                                         int E, int NB, int chunk) {
    __shared__ int lh[MAXNB];
    int c = blockIdx.x;
    for (int i = threadIdx.x; i < NB; i += 256) lh[i] = 0;
    __syncthreads();
    int beg = c * chunk, end = min(beg + chunk, E);
    for (int e = beg + threadIdx.x; e < end; e += 256) atomicAdd(&lh[dst[e] >> BSHIFT], 1);
    __syncthreads();
    for (int i = threadIdx.x; i < NB; i += 256) histG[i * NCH + c] = lh[i];  // bucket-major
}

// ---------------- 3-kernel exclusive scan of histG (L entries) ----------------

__global__ void block_sum_kernel(const int* __restrict__ in, int* __restrict__ partials, int L) {
    __shared__ int sdata[256];
    int base = blockIdx.x * SCAN_CHUNK;
    int sum = 0;
    for (int i = threadIdx.x; i < SCAN_CHUNK; i += 256) {
        int idx = base + i;
        sum += (idx < L) ? in[idx] : 0;
    }
    sdata[threadIdx.x] = sum;
    __syncthreads();
    for (int s = 128; s > 0; s >>= 1) {
        if (threadIdx.x < s) sdata[threadIdx.x] += sdata[threadIdx.x + s];
        __syncthreads();
    }
    if (threadIdx.x == 0) partials[blockIdx.x] = sdata[0];
}

__global__ void scan_partials_kernel(int* __restrict__ partials, int nb,
                                     int* __restrict__ out, int L) {
    if (threadIdx.x == 0 && blockIdx.x == 0) {
        int acc = 0;
        for (int i = 0; i < nb; i++) { int v = partials[i]; partials[i] = acc; acc += v; }
        out[L] = acc;  // total = E
    }
}

__global__ void scan_write_kernel(const int* __restrict__ in, const int* __restrict__ partials,
                                  int* __restrict__ out, int L) {
    __shared__ int sdata[256];
    int base = blockIdx.x * SCAN_CHUNK;
    int tbase = base + threadIdx.x * 4;
    int vals[4];
    int tsum = 0;
    #pragma unroll
    for (int j = 0; j < 4; j++) {
        int idx = tbase + j;
        vals[j] = (idx < L) ? in[idx] : 0;
        tsum += vals[j];
    }
    sdata[threadIdx.x] = tsum;
    __syncthreads();
    for (int s = 1; s < 256; s <<= 1) {
        int v = (threadIdx.x >= s) ? sdata[threadIdx.x - s] : 0;
        __syncthreads();
        sdata[threadIdx.x] += v;
        __syncthreads();
    }
    int excl = (threadIdx.x == 0) ? 0 : sdata[threadIdx.x - 1];
    int offset = partials[blockIdx.x] + excl;
    #pragma unroll
    for (int j = 0; j < 4; j++) {
        int idx = tbase + j;
        if (idx < L) out[idx] = offset;
        offset += vals[j];
    }
}

// ---------------- pass B: scatter packed (src|ldst<<24) into (bucket,chunk) windows ----------------

__global__ __launch_bounds__(256) void chunk_scatter_kernel(const int* __restrict__ src,
                                                            const int* __restrict__ dst,
                                                            const int* __restrict__ histBase,
                                                            int* __restrict__ binned,
                                                            int E, int NB, int chunk) {
    __shared__ int cur[MAXNB];
    int c = blockIdx.x;
    for (int i = threadIdx.x; i < NB; i += 256) cur[i] = histBase[i * NCH + c];
    __syncthreads();
    int beg = c * chunk, end = min(beg + chunk, E);
    for (int e = beg + threadIdx.x; e < end; e += 256) {
        int s = src[e], d = dst[e];
        int pos = atomicAdd(&cur[d >> BSHIFT], 1);
        binned[pos] = s | ((d & (BNODES - 1)) << 24);
    }
}

// ---------------- fused per-bucket: node hist + local scan -> row_ptr/dinv + CSR scatter ----------------

__global__ __launch_bounds__(256) void bucket_finalize_kernel(const int* __restrict__ binned,
                                                              const int* __restrict__ histBase,
                                                              int* __restrict__ row_ptr,
                                                              float* __restrict__ dinv,
                                                              int* __restrict__ srcidx, int n) {
    __shared__ int cl[BNODES];   // counts, then cursors
    __shared__ int sl[BNODES];   // scan workspace
    int b = blockIdx.x;
    int tid = threadIdx.x;
    cl[tid] = 0;
    __syncthreads();
    int beg = histBase[b * NCH], end = histBase[(b + 1) * NCH];
    for (int e = beg + tid; e < end; e += 256)
        atomicAdd(&cl[(uint_t)binned[e] >> 24], 1);
    __syncthreads();
    int mycnt = cl[tid];
    sl[tid] = mycnt;
    __syncthreads();
    for (int s = 1; s < 256; s <<= 1) {           // Hillis-Steele inclusive
        int v = (tid >= s) ? sl[tid - s] : 0;
        __syncthreads();
        sl[tid] += v;
        __syncthreads();
    }
    int excl = tid ? sl[tid - 1] : 0;
    int myrp = beg + excl;
    cl[tid] = myrp;                               // becomes fill cursor
    int node = (b << BSHIFT) + tid;
    if (node < n) {
        row_ptr[node] = myrp;
        dinv[node] = rsqrtf((float)(mycnt + 1));  // +1 self-loop
        if (node == n - 1) row_ptr[n] = myrp + mycnt;
    }
    __syncthreads();
    for (int e = beg + tid; e < end; e += 256) {  // binned slice is L2-hot from pass 1
        int v = binned[e];
        int pos = atomicAdd(&cl[(uint_t)v >> 24], 1);
        srcidx[pos] = v & 0xFFFFFF;
    }
}

// ---------------- dense transform: g[r][c] = bf16(dinv[r] * sum_k in[r][k]*W[k][c]) ----------------

__global__ __launch_bounds__(256) void transform_kernel(const float* __restrict__ in,
                                                        const float* __restrict__ W,
                                                        const float* __restrict__ dinv,
                                                        ushort_t* __restrict__ g, int n) {
    __shared__ float Ws[64 * 64];
    for (int i = threadIdx.x; i < 64 * 64; i += 256) Ws[i] = W[i];
    __syncthreads();
    int lane = threadIdx.x & 63;
    int wave = (blockIdx.x * 256 + threadIdx.x) >> 6;
    int nwaves = gridDim.x * 4;
    for (int r = wave; r < n; r += nwaves) {
        float xv = in[r * 64 + lane];
        float acc = 0.f;
        #pragma unroll
        for (int k = 0; k < 64; k++) {
            float xk = __shfl(xv, k, 64);
            acc = fmaf(xk, Ws[k * 64 + lane], acc);
        }
        g[r * 64 + lane] = f32_to_bf16(acc * dinv[r]);
    }
}

// ---------------- aggregate: out[i] = dinv[i]*(g[i] + sum_{j in N(i)} g[j]) + b ----------------

__global__ __launch_bounds__(256) void aggregate_kernel(const ushort_t* __restrict__ g,
                                                        const int* __restrict__ row_ptr,
                                                        const int* __restrict__ srcidx,
                                                        const float* __restrict__ dinv,
                                                        const float* __restrict__ b,
                                                        float* __restrict__ out, int n, int relu) {
    int lane = threadIdx.x & 63;
    int node = (blockIdx.x * 256 + threadIdx.x) >> 6;
    if (node >= n) return;
    node = __builtin_amdgcn_readfirstlane(node);
    int beg = row_ptr[node];
    int end = row_ptr[node + 1];
    float acc = bf16_to_f32(g[node * 64 + lane]);  // self-loop (g already has dinv factor)
    int e = beg;
    for (; e + 8 <= end; e += 8) {
        int s0 = srcidx[e + 0], s1 = srcidx[e + 1], s2 = srcidx[e + 2], s3 = srcidx[e + 3];
        int s4 = srcidx[e + 4], s5 = srcidx[e + 5], s6 = srcidx[e + 6], s7 = srcidx[e + 7];
        float v0 = bf16_to_f32(g[s0 * 64 + lane]);
        float v1 = bf16_to_f32(g[s1 * 64 + lane]);
        float v2 = bf16_to_f32(g[s2 * 64 + lane]);
        float v3 = bf16_to_f32(g[s3 * 64 + lane]);
        float v4 = bf16_to_f32(g[s4 * 64 + lane]);
        float v5 = bf16_to_f32(g[s5 * 64 + lane]);
        float v6 = bf16_to_f32(g[s6 * 64 + lane]);
        float v7 = bf16_to_f32(g[s7 * 64 + lane]);
        acc += ((v0 + v1) + (v2 + v3)) + ((v4 + v5) + (v6 + v7));
    }
    for (; e < end; ++e) acc += bf16_to_f32(g[srcidx[e] * 64 + lane]);
    float o = fmaf(dinv[node], acc, b[lane]);
    out[node * 64 + lane] = relu ? fmaxf(o, 0.f) : o;
}

extern "C" void kernel_launch(void* const* d_in, const int* in_sizes, int n_in,
                              void* d_out, int out_size, void* d_ws, size_t ws_size,
                              hipStream_t stream) {
    const float* x  = (const float*)d_in[0];
    const int*   ei = (const int*)d_in[1];
    const float* W1 = (const float*)d_in[2];
    const float* b1 = (const float*)d_in[3];
    const float* W2 = (const float*)d_in[4];
    const float* b2 = (const float*)d_in[5];
    float* out = (float*)d_out;

    const int n = in_sizes[0] / 64;      // 100000
    const int E = in_sizes[1] / 2;       // 3200000
    const int* src = ei;
    const int* dst = ei + E;
    const int NB = (n + BNODES - 1) >> BSHIFT;         // 391 buckets
    const int chunk = (E + NCH - 1) / NCH;             // 12500 edges/chunk
    const int L = NB * NCH;                            // histogram length

    // workspace carve-up (256B aligned)
    char* ws = (char*)d_ws;
    size_t off = 0;
    auto carve = [&](size_t bytes) { char* p = ws + off; off = (off + bytes + 255) & ~(size_t)255; return p; };
    int*      row_ptr  = (int*)     carve((size_t)(n + 1) * 4);
    int*      partials = (int*)     carve(4096);
    float*    dinv     = (float*)   carve((size_t)n * 4);
    int*      histG    = (int*)     carve((size_t)L * 4);        // per-(bucket,chunk) counts
    int*      histBase = (int*)     carve((size_t)(L + 1) * 4);  // scanned offsets
    int*      srcidx   = (int*)     carve((size_t)E * 4);
    int*      binned   = (int*)     carve((size_t)E * 4);        // packed src|ldst<<24
    ushort_t* g        = (ushort_t*)carve((size_t)n * 64 * 2);   // bf16 scaled features

    const int nbs_hist = (L + SCAN_CHUNK - 1) / SCAN_CHUNK;

    // ---- CSR build via chunked two-pass radix partition (shared by both layers) ----
    chunk_hist_kernel<<<NCH, 256, 0, stream>>>(dst, histG, E, NB, chunk);
    block_sum_kernel<<<nbs_hist, 256, 0, stream>>>(histG, partials, L);
    scan_partials_kernel<<<1, 64, 0, stream>>>(partials, nbs_hist, histBase, L);
    scan_write_kernel<<<nbs_hist, 256, 0, stream>>>(histG, partials, histBase, L);
    chunk_scatter_kernel<<<NCH, 256, 0, stream>>>(src, dst, histBase, binned, E, NB, chunk);
    bucket_finalize_kernel<<<NB, 256, 0, stream>>>(binned, histBase, row_ptr, dinv, srcidx, n);

    const int agg_grid = (n * 64 + 255) / 256;   // one wave per node

    // ---- layer 1: g = bf16((x@W1)*dinv) ; h1 = relu(dinv*(agg(g)+g)+b1) -> d_out (f32) ----
    transform_kernel<<<1024, 256, 0, stream>>>(x, W1, dinv, g, n);
    aggregate_kernel<<<agg_grid, 256, 0, stream>>>(g, row_ptr, srcidx, dinv, b1, out, n, 1);

    // ---- layer 2: g = bf16((h1@W2)*dinv) ; out = dinv*(agg(g)+g)+b2 ----
    transform_kernel<<<1024, 256, 0, stream>>>(out, W2, dinv, g, n);
    aggregate_kernel<<<agg_grid, 256, 0, stream>>>(g, row_ptr, srcidx, dinv, b2, out, n, 0);
}

// Round 5
// 272.961 us; speedup vs baseline: 3.3194x; 1.3412x over previous
//
#include <hip/hip_runtime.h>

typedef unsigned short ushort_t;
typedef unsigned int uint_t;

#define SCAN_CHUNK 1024
#define NCH 256          // edge chunks (= pass-A/B grid)
#define BSHIFT 8
#define BNODES 256       // nodes per bucket
#define MAXNB 512        // max buckets (n <= 131072)

__device__ __forceinline__ ushort_t f32_to_bf16(float f) {
    uint_t u = __float_as_uint(f);
    return (ushort_t)((u + 0x7FFF + ((u >> 16) & 1)) >> 16);  // RNE
}
__device__ __forceinline__ float bf16_to_f32(ushort_t h) {
    return __uint_as_float((uint_t)h << 16);
}

// ---------------- pass A: per-chunk bucket histogram ----------------

__global__ __launch_bounds__(256) void chunk_hist_kernel(const int* __restrict__ dst,
                                                         int* __restrict__ histG,
                                                         int E, int NB, int chunk) {
    __shared__ int lh[MAXNB];
    int c = blockIdx.x;
    for (int i = threadIdx.x; i < NB; i += 256) lh[i] = 0;
    __syncthreads();
    int beg = c * chunk, end = min(beg + chunk, E);
    for (int e = beg + threadIdx.x; e < end; e += 256) atomicAdd(&lh[dst[e] >> BSHIFT], 1);
    __syncthreads();
    for (int i = threadIdx.x; i < NB; i += 256) histG[i * NCH + c] = lh[i];  // bucket-major
}

// ---------------- 3-kernel exclusive scan of histG (L entries) ----------------

__global__ void block_sum_kernel(const int* __restrict__ in, int* __restrict__ partials, int L) {
    __shared__ int sdata[256];
    int base = blockIdx.x * SCAN_CHUNK;
    int sum = 0;
    for (int i = threadIdx.x; i < SCAN_CHUNK; i += 256) {
        int idx = base + i;
        sum += (idx < L) ? in[idx] : 0;
    }
    sdata[threadIdx.x] = sum;
    __syncthreads();
    for (int s = 128; s > 0; s >>= 1) {
        if (threadIdx.x < s) sdata[threadIdx.x] += sdata[threadIdx.x + s];
        __syncthreads();
    }
    if (threadIdx.x == 0) partials[blockIdx.x] = sdata[0];
}

__global__ void scan_partials_kernel(int* __restrict__ partials, int nb,
                                     int* __restrict__ out, int L) {
    if (threadIdx.x == 0 && blockIdx.x == 0) {
        int acc = 0;
        for (int i = 0; i < nb; i++) { int v = partials[i]; partials[i] = acc; acc += v; }
        out[L] = acc;  // total = E
    }
}

__global__ void scan_write_kernel(const int* __restrict__ in, const int* __restrict__ partials,
                                  int* __restrict__ out, int L) {
    __shared__ int sdata[256];
    int base = blockIdx.x * SCAN_CHUNK;
    int tbase = base + threadIdx.x * 4;
    int vals[4];
    int tsum = 0;
    #pragma unroll
    for (int j = 0; j < 4; j++) {
        int idx = tbase + j;
        vals[j] = (idx < L) ? in[idx] : 0;
        tsum += vals[j];
    }
    sdata[threadIdx.x] = tsum;
    __syncthreads();
    for (int s = 1; s < 256; s <<= 1) {
        int v = (threadIdx.x >= s) ? sdata[threadIdx.x - s] : 0;
        __syncthreads();
        sdata[threadIdx.x] += v;
        __syncthreads();
    }
    int excl = (threadIdx.x == 0) ? 0 : sdata[threadIdx.x - 1];
    int offset = partials[blockIdx.x] + excl;
    #pragma unroll
    for (int j = 0; j < 4; j++) {
        int idx = tbase + j;
        if (idx < L) out[idx] = offset;
        offset += vals[j];
    }
}

// ---------------- pass B: scatter packed (src|ldst<<24) into (bucket,chunk) windows ----------------

__global__ __launch_bounds__(256) void chunk_scatter_kernel(const int* __restrict__ src,
                                                            const int* __restrict__ dst,
                                                            const int* __restrict__ histBase,
                                                            int* __restrict__ binned,
                                                            int E, int NB, int chunk) {
    __shared__ int cur[MAXNB];
    int c = blockIdx.x;
    for (int i = threadIdx.x; i < NB; i += 256) cur[i] = histBase[i * NCH + c];
    __syncthreads();
    int beg = c * chunk, end = min(beg + chunk, E);
    for (int e = beg + threadIdx.x; e < end; e += 256) {
        int s = src[e], d = dst[e];
        int pos = atomicAdd(&cur[d >> BSHIFT], 1);
        binned[pos] = s | ((d & (BNODES - 1)) << 24);
    }
}

// ---------------- fused per-bucket: node hist + local scan -> row_ptr/dinv + CSR scatter ----------------

__global__ __launch_bounds__(256) void bucket_finalize_kernel(const int* __restrict__ binned,
                                                              const int* __restrict__ histBase,
                                                              int* __restrict__ row_ptr,
                                                              float* __restrict__ dinv,
                                                              int* __restrict__ srcidx, int n) {
    __shared__ int cl[BNODES];   // counts, then cursors
    __shared__ int sl[BNODES];   // scan workspace
    int b = blockIdx.x;
    int tid = threadIdx.x;
    cl[tid] = 0;
    __syncthreads();
    int beg = histBase[b * NCH], end = histBase[(b + 1) * NCH];
    for (int e = beg + tid; e < end; e += 256)
        atomicAdd(&cl[(uint_t)binned[e] >> 24], 1);
    __syncthreads();
    int mycnt = cl[tid];
    sl[tid] = mycnt;
    __syncthreads();
    for (int s = 1; s < 256; s <<= 1) {           // Hillis-Steele inclusive
        int v = (tid >= s) ? sl[tid - s] : 0;
        __syncthreads();
        sl[tid] += v;
        __syncthreads();
    }
    int excl = tid ? sl[tid - 1] : 0;
    int myrp = beg + excl;
    cl[tid] = myrp;                               // becomes fill cursor
    int node = (b << BSHIFT) + tid;
    if (node < n) {
        row_ptr[node] = myrp;
        dinv[node] = rsqrtf((float)(mycnt + 1));  // +1 self-loop
        if (node == n - 1) row_ptr[n] = myrp + mycnt;
    }
    __syncthreads();
    for (int e = beg + tid; e < end; e += 256) {  // binned slice is L2-hot from pass 1
        int v = binned[e];
        int pos = atomicAdd(&cl[(uint_t)v >> 24], 1);
        srcidx[pos] = v & 0xFFFFFF;
    }
}

// ---------------- dense transform: g[r][c] = bf16(dinv[r] * sum_k in[r][k]*W[k][c]) ----------------
// W column held in 64 VGPRs; x rows staged 4-at-a-time in a wave-private LDS slice,
// read back as uniform-address ds_read_b128 broadcasts (65 DS ops / 4 rows).

__global__ __launch_bounds__(256) void transform_kernel(const float* __restrict__ in,
                                                        const float* __restrict__ W,
                                                        const float* __restrict__ dinv,
                                                        ushort_t* __restrict__ g, int n) {
    __shared__ float xs[4 * 256];                 // 4 waves/block x (4 rows x 64 floats)
    int lane = threadIdx.x & 63;
    int wslot = threadIdx.x >> 6;
    float* myxs = &xs[wslot * 256];

    float wreg[64];                               // W[k][lane], k=0..63 (static idx -> VGPRs)
    #pragma unroll
    for (int k = 0; k < 64; k++) wreg[k] = W[k * 64 + lane];

    int wave = (blockIdx.x * 256 + threadIdx.x) >> 6;
    int nwaves = gridDim.x * 4;
    int ngroups = (n + 3) >> 2;
    for (int grp = wave; grp < ngroups; grp += nwaves) {
        int r0 = grp * 4;
        if (r0 + 4 <= n) {
            // stage 4 rows (1KB): lane brings 16B, coalesced
            float4 xv = *reinterpret_cast<const float4*>(&in[(size_t)r0 * 64 + lane * 4]);
            *reinterpret_cast<float4*>(&myxs[lane * 4]) = xv;
            float acc0 = 0.f, acc1 = 0.f, acc2 = 0.f, acc3 = 0.f;
            #pragma unroll
            for (int k4 = 0; k4 < 16; k4++) {
                float4 a = *reinterpret_cast<const float4*>(&myxs[0 * 64 + k4 * 4]);
                float4 b = *reinterpret_cast<const float4*>(&myxs[1 * 64 + k4 * 4]);
                float4 c = *reinterpret_cast<const float4*>(&myxs[2 * 64 + k4 * 4]);
                float4 d = *reinterpret_cast<const float4*>(&myxs[3 * 64 + k4 * 4]);
                float w0 = wreg[k4 * 4 + 0], w1 = wreg[k4 * 4 + 1];
                float w2 = wreg[k4 * 4 + 2], w3 = wreg[k4 * 4 + 3];
                acc0 = fmaf(a.x, w0, acc0); acc0 = fmaf(a.y, w1, acc0);
                acc0 = fmaf(a.z, w2, acc0); acc0 = fmaf(a.w, w3, acc0);
                acc1 = fmaf(b.x, w0, acc1); acc1 = fmaf(b.y, w1, acc1);
                acc1 = fmaf(b.z, w2, acc1); acc1 = fmaf(b.w, w3, acc1);
                acc2 = fmaf(c.x, w0, acc2); acc2 = fmaf(c.y, w1, acc2);
                acc2 = fmaf(c.z, w2, acc2); acc2 = fmaf(c.w, w3, acc2);
                acc3 = fmaf(d.x, w0, acc3); acc3 = fmaf(d.y, w1, acc3);
                acc3 = fmaf(d.z, w2, acc3); acc3 = fmaf(d.w, w3, acc3);
            }
            g[(size_t)(r0 + 0) * 64 + lane] = f32_to_bf16(acc0 * dinv[r0 + 0]);
            g[(size_t)(r0 + 1) * 64 + lane] = f32_to_bf16(acc1 * dinv[r0 + 1]);
            g[(size_t)(r0 + 2) * 64 + lane] = f32_to_bf16(acc2 * dinv[r0 + 2]);
            g[(size_t)(r0 + 3) * 64 + lane] = f32_to_bf16(acc3 * dinv[r0 + 3]);
        } else {
            for (int r = r0; r < n; r++) {        // tail (n%4 != 0)
                float acc = 0.f;
                #pragma unroll
                for (int k = 0; k < 64; k++) acc = fmaf(in[(size_t)r * 64 + k], wreg[k], acc);
                g[(size_t)r * 64 + lane] = f32_to_bf16(acc * dinv[r]);
            }
        }
    }
}

// ---------------- aggregate: out[i] = dinv[i]*(g[i] + sum_{j in N(i)} g[j]) + b ----------------

__global__ __launch_bounds__(256) void aggregate_kernel(const ushort_t* __restrict__ g,
                                                        const int* __restrict__ row_ptr,
                                                        const int* __restrict__ srcidx,
                                                        const float* __restrict__ dinv,
                                                        const float* __restrict__ b,
                                                        float* __restrict__ out, int n, int relu) {
    int lane = threadIdx.x & 63;
    int node = (blockIdx.x * 256 + threadIdx.x) >> 6;
    if (node >= n) return;
    node = __builtin_amdgcn_readfirstlane(node);
    int beg = row_ptr[node];
    int end = row_ptr[node + 1];
    float acc = bf16_to_f32(g[(size_t)node * 64 + lane]);  // self-loop
    int e = beg;
    for (; e + 8 <= end; e += 8) {
        int s0 = srcidx[e + 0], s1 = srcidx[e + 1], s2 = srcidx[e + 2], s3 = srcidx[e + 3];
        int s4 = srcidx[e + 4], s5 = srcidx[e + 5], s6 = srcidx[e + 6], s7 = srcidx[e + 7];
        float v0 = bf16_to_f32(g[(size_t)s0 * 64 + lane]);
        float v1 = bf16_to_f32(g[(size_t)s1 * 64 + lane]);
        float v2 = bf16_to_f32(g[(size_t)s2 * 64 + lane]);
        float v3 = bf16_to_f32(g[(size_t)s3 * 64 + lane]);
        float v4 = bf16_to_f32(g[(size_t)s4 * 64 + lane]);
        float v5 = bf16_to_f32(g[(size_t)s5 * 64 + lane]);
        float v6 = bf16_to_f32(g[(size_t)s6 * 64 + lane]);
        float v7 = bf16_to_f32(g[(size_t)s7 * 64 + lane]);
        acc += ((v0 + v1) + (v2 + v3)) + ((v4 + v5) + (v6 + v7));
    }
    for (; e < end; ++e) acc += bf16_to_f32(g[(size_t)srcidx[e] * 64 + lane]);
    float o = fmaf(dinv[node], acc, b[lane]);
    out[(size_t)node * 64 + lane] = relu ? fmaxf(o, 0.f) : o;
}

extern "C" void kernel_launch(void* const* d_in, const int* in_sizes, int n_in,
                              void* d_out, int out_size, void* d_ws, size_t ws_size,
                              hipStream_t stream) {
    const float* x  = (const float*)d_in[0];
    const int*   ei = (const int*)d_in[1];
    const float* W1 = (const float*)d_in[2];
    const float* b1 = (const float*)d_in[3];
    const float* W2 = (const float*)d_in[4];
    const float* b2 = (const float*)d_in[5];
    float* out = (float*)d_out;

    const int n = in_sizes[0] / 64;      // 100000
    const int E = in_sizes[1] / 2;       // 3200000
    const int* src = ei;
    const int* dst = ei + E;
    const int NB = (n + BNODES - 1) >> BSHIFT;         // 391 buckets
    const int chunk = (E + NCH - 1) / NCH;             // 12500 edges/chunk
    const int L = NB * NCH;                            // histogram length

    // workspace carve-up (256B aligned)
    char* ws = (char*)d_ws;
    size_t off = 0;
    auto carve = [&](size_t bytes) { char* p = ws + off; off = (off + bytes + 255) & ~(size_t)255; return p; };
    int*      row_ptr  = (int*)     carve((size_t)(n + 1) * 4);
    int*      partials = (int*)     carve(4096);
    float*    dinv     = (float*)   carve((size_t)n * 4);
    int*      histG    = (int*)     carve((size_t)L * 4);        // per-(bucket,chunk) counts
    int*      histBase = (int*)     carve((size_t)(L + 1) * 4);  // scanned offsets
    int*      srcidx   = (int*)     carve((size_t)E * 4);
    int*      binned   = (int*)     carve((size_t)E * 4);        // packed src|ldst<<24
    ushort_t* g        = (ushort_t*)carve((size_t)n * 64 * 2);   // bf16 scaled features

    const int nbs_hist = (L + SCAN_CHUNK - 1) / SCAN_CHUNK;

    // ---- CSR build via chunked two-pass radix partition (shared by both layers) ----
    chunk_hist_kernel<<<NCH, 256, 0, stream>>>(dst, histG, E, NB, chunk);
    block_sum_kernel<<<nbs_hist, 256, 0, stream>>>(histG, partials, L);
    scan_partials_kernel<<<1, 64, 0, stream>>>(partials, nbs_hist, histBase, L);
    scan_write_kernel<<<nbs_hist, 256, 0, stream>>>(histG, partials, histBase, L);
    chunk_scatter_kernel<<<NCH, 256, 0, stream>>>(src, dst, histBase, binned, E, NB, chunk);
    bucket_finalize_kernel<<<NB, 256, 0, stream>>>(binned, histBase, row_ptr, dinv, srcidx, n);

    const int agg_grid = (n * 64 + 255) / 256;   // one wave per node

    // ---- layer 1: g = bf16((x@W1)*dinv) ; h1 = relu(dinv*(agg(g)+g)+b1) -> d_out (f32) ----
    transform_kernel<<<2048, 256, 0, stream>>>(x, W1, dinv, g, n);
    aggregate_kernel<<<agg_grid, 256, 0, stream>>>(g, row_ptr, srcidx, dinv, b1, out, n, 1);

    // ---- layer 2: g = bf16((h1@W2)*dinv) ; out = dinv*(agg(g)+g)+b2 ----
    transform_kernel<<<2048, 256, 0, stream>>>(out, W2, dinv, g, n);
    aggregate_kernel<<<agg_grid, 256, 0, stream>>>(g, row_ptr, srcidx, dinv, b2, out, n, 0);
}